// Round 3
// baseline (205.835 us; speedup 1.0000x reference)
//
#include <hip/hip_runtime.h>
#include <math.h>

typedef unsigned short u16;
typedef unsigned int   u32;
typedef float f32x4 __attribute__((ext_vector_type(4)));

#define OUTSZ 7
#define B_ 2
#define C_ 256
#define R_ 256
#define N_ (B_ * R_)

// NHWC bf16 scratch: pixel index -> 256 bf16 channels (512B records).
// per-batch level pixel bases: L0:0 L1:80000 L2:100000 L3:105000 (b-major within level)
#define PX_TOTAL 106250
#define WS_NEEDED ((size_t)PX_TOTAL * 256 * 2)

__device__ __forceinline__ u16 f2bf(float v) {
    u32 u = __float_as_uint(v);
    u += 0x7fffu + ((u >> 16) & 1u);           // RNE to bf16
    return (u16)(u >> 16);
}

__device__ __forceinline__ u32 pack2bf(float a, float b) {
    return (u32)f2bf(a) | ((u32)f2bf(b) << 16);
}

// ---------------- NCHW fp32 -> NHWC bf16: reg pack + 16KB swizzled-LDS (2 half-stores) ----
// Wave owns 16 consecutive channels. Each thread: 16 nontemporal float4 row
// loads (all in flight), packs bf16 uint4 in registers, stages each 128-px
// half through a 16KB px-major swizzled LDS tile, stores full 128B-line
// segments. 16KB LDS -> 8 blocks/CU residency (vs 5 at 32KB).
// grid = (210 px-tiles, 4 ch-blocks, 2 batches), block 256.
__global__ __launch_bounds__(256, 8) void nhwc_cast(
    const float* __restrict__ f0, const float* __restrict__ f1,
    const float* __restrict__ f2, const float* __restrict__ f3,
    u16* __restrict__ dst)
{
    __shared__ u32 lds32[128 * 32];   // 16 KB: 128 px, 8 uint4-quads per px, swizzled
    const int tid  = threadIdx.x;
    const int lane = tid & 63;
    const int wave = tid >> 6;

    const int t  = blockIdx.x;
    const int cb = blockIdx.y;
    const int b  = blockIdx.z;
    const float* src; int HWsz, dstBase, ft;
    if      (t < 157) { src = f0; HWsz = 40000; dstBase = 0;      ft = t;       }
    else if (t < 197) { src = f1; HWsz = 10000; dstBase = 80000;  ft = t - 157; }
    else if (t < 207) { src = f2; HWsz = 2500;  dstBase = 100000; ft = t - 197; }
    else              { src = f3; HWsz = 625;   dstBase = 105000; ft = t - 207; }

    const int fbase = ft * 256;
    const int cw    = cb * 64 + wave * 16;       // this wave's 16-channel base
    const int rem   = HWsz - fbase;              // >= 1
    const int p0    = 4 * lane;
    const bool vec  = ((HWsz & 3) == 0) && (p0 + 3 < rem);

    const float* base = src + ((size_t)(b * C_ + cw)) * HWsz + fbase;

    // 1) all 16 row loads in flight (nontemporal: input not reused, keep L3 for scratch)
    float f[16][4];
    #pragma unroll
    for (int i = 0; i < 16; ++i) {
        const float* row = base + (size_t)i * HWsz;
        if (vec) {
            f32x4 v = __builtin_nontemporal_load((const f32x4*)(row + p0));
            f[i][0] = v.x; f[i][1] = v.y; f[i][2] = v.z; f[i][3] = v.w;
        } else {
            #pragma unroll
            for (int k = 0; k < 4; ++k)
                f[i][k] = (p0 + k < rem) ? row[p0 + k] : 0.0f;
        }
    }

    const int half  = lane >> 5;                 // which 128-px half this thread's px fall in
    const int pl0   = p0 & 127;                  // px offset within half
    const int maxpx = rem < 256 ? rem : 256;

    #pragma unroll
    for (int h = 0; h < 2; ++h) {
        // 2) pack + swizzled LDS write (only lanes whose pixels are in half h)
        if (half == h) {
            #pragma unroll
            for (int r = 0; r < 2; ++r) {
                #pragma unroll
                for (int j = 0; j < 4; ++j) {
                    uint4 o;
                    o.x = pack2bf(f[r * 8 + 0][j], f[r * 8 + 1][j]);
                    o.y = pack2bf(f[r * 8 + 2][j], f[r * 8 + 3][j]);
                    o.z = pack2bf(f[r * 8 + 4][j], f[r * 8 + 5][j]);
                    o.w = pack2bf(f[r * 8 + 6][j], f[r * 8 + 7][j]);
                    const int q = (wave * 2 + r) ^ (lane & 7);   // ((px>>2)&7) == lane&7
                    *(uint4*)&lds32[(pl0 + j) * 32 + q * 4] = o;
                }
            }
        }
        __syncthreads();

        // 3) full-line stores: (px-local, sub) -> 16B; 8 lanes/px = 128B contiguous
        #pragma unroll
        for (int i = 0; i < 4; ++i) {
            const int idx = i * 256 + tid;
            const int pxl = idx >> 3;
            const int sub = idx & 7;
            const int px  = h * 128 + pxl;
            if (px < maxpx) {
                const int q = sub ^ ((pxl >> 2) & 7);
                uint4 o = *(const uint4*)&lds32[pxl * 32 + q * 4];
                *(uint4*)(dst + (size_t)(dstBase + b * HWsz + fbase + px) * 256 + cb * 64 + sub * 8) = o;
            }
        }
        if (h == 0) __syncthreads();
    }
}

// ---------------- gather: block owns (ROI n, cell range); all 256 ch per load ----
// blockIdx.x = g: g=0 -> cells 0..27 (rows 0-3), g=1 -> cells 28..48 (rows 4-6).
// Per record: ONE uint2-per-lane load = 512B = all 256 channels (halves wave
// load-instr count vs 128-ch split). Bilinear tables computed in-block
// (prep kernel fused away). Output staged through LDS for coalesced stores.
__device__ __forceinline__ void acc4(float4& a, uint2 u, float w) {
    a.x += w * __uint_as_float(u.x << 16);
    a.y += w * __uint_as_float(u.x & 0xffff0000u);
    a.z += w * __uint_as_float(u.y << 16);
    a.w += w * __uint_as_float(u.y & 0xffff0000u);
}

template<int NC, int CB>
__device__ __forceinline__ void store_out(const float* lds, float* out, int n) {
    #pragma unroll 4
    for (int i = threadIdx.x; i < 256 * NC; i += 256) {
        const int c = i / NC;
        const int j = i - c * NC;
        __builtin_nontemporal_store(lds[j * 260 + c],
                                    out + ((size_t)(n * C_ + c)) * 49 + CB + j);
    }
}

__global__ __launch_bounds__(256) void roi_gather(
    const u16* __restrict__ ws16, const float* __restrict__ boxes,
    float* __restrict__ out)
{
    __shared__ float lds[28 * 260];            // 29120 B (cell-major, 256ch + pad)
    __shared__ float s_wy0[14], s_wy1[14], s_wx0[14], s_wx1[14];
    __shared__ int   s_yl[14], s_yh[14], s_xl[14], s_xh[14];
    __shared__ int   s_base, s_W;

    const int g    = blockIdx.x;
    const int n    = blockIdx.y;
    const int tid  = threadIdx.x;
    const int lane = tid & 63;
    const int wave = tid >> 6;

    // ---- fused prep: threads 0..13 -> y entries, 14..27 -> x entries ----
    if (tid < 28) {
        const float* bx = boxes + (size_t)n * 4;
        float x1 = bx[0], y1 = bx[1], x2 = bx[2], y2 = bx[3];
        float area = (x2 - x1) * (y2 - y1);
        float lf = floorf(4.0f + log2f(sqrtf(area) / 224.0f + 1e-8f));
        lf = fminf(fmaxf(lf, 2.0f), 5.0f);
        int lvl = (int)lf - 2;
        const float scales[4] = {0.25f, 0.125f, 0.0625f, 0.03125f};
        const int   sizes[4]  = {200, 100, 50, 25};
        const int   bases[4]  = {0, 80000, 100000, 105000};
        float scale = scales[lvl];
        int   HW    = sizes[lvl];
        float lim = (float)HW, cap = lim - 1.0f;
        float fx1 = x1 * scale, fy1 = y1 * scale;
        float bw = fmaxf(x2 * scale - fx1, 1.0f) / (float)OUTSZ;
        float bh = fmaxf(y2 * scale - fy1, 1.0f) / (float)OUTSZ;
        if (tid == 0) { s_base = bases[lvl] + (n >> 8) * HW * HW; s_W = HW; }

        const int  i   = (tid < 14) ? tid : tid - 14;
        const bool isy = tid < 14;
        float o  = isy ? fy1 : fx1;
        float st = isy ? bh  : bw;
        float gq = (float)(i >> 1) + ((float)(i & 1) + 0.5f) * 0.5f;
        float c = o + st * gq;
        bool  v = (c > -1.0f) && (c < lim);
        float cc = fmaxf(c, 0.0f);
        float low = floorf(cc);
        bool  edge = low >= cap;
        low = fminf(low, cap);
        float high = fminf(low + 1.0f, cap);
        float fr = edge ? 0.0f : (cc - low);
        float w0 = v ? (1.0f - fr) : 0.0f;
        float w1 = v ? fr : 0.0f;
        if (isy) { s_yl[i] = (int)low; s_yh[i] = (int)high; s_wy0[i] = w0; s_wy1[i] = w1; }
        else     { s_xl[i] = (int)low; s_xh[i] = (int)high; s_wx0[i] = w0; s_wx1[i] = w1; }
    }
    __syncthreads();

    const int base = s_base, W = s_W;
    const int CB = g ? 28 : 0;
    const int NC = g ? 21 : 28;

    for (int cell = CB + wave; cell < CB + NC; cell += 4) {
        const int cu = __builtin_amdgcn_readfirstlane(cell);
        const int oy = cu / 7, ox = cu - oy * 7;
        float4 acc = {0.0f, 0.0f, 0.0f, 0.0f};
        #pragma unroll
        for (int sy = 0; sy < 2; ++sy) {
            const int ei = oy * 2 + sy;
            const float wy0 = s_wy0[ei], wy1 = s_wy1[ei];
            const int rl = base + s_yl[ei] * W;
            const int rh = base + s_yh[ei] * W;
            #pragma unroll
            for (int sx = 0; sx < 2; ++sx) {
                const int ej = ox * 2 + sx;
                const float w00 = wy0 * s_wx0[ej], w01 = wy0 * s_wx1[ej];
                const float w10 = wy1 * s_wx0[ej], w11 = wy1 * s_wx1[ej];
                const int xl = s_xl[ej], xh = s_xh[ej];
                uint2 u00 = ((const uint2*)(ws16 + (size_t)(rl + xl) * 256))[lane];
                uint2 u01 = ((const uint2*)(ws16 + (size_t)(rl + xh) * 256))[lane];
                uint2 u10 = ((const uint2*)(ws16 + (size_t)(rh + xl) * 256))[lane];
                uint2 u11 = ((const uint2*)(ws16 + (size_t)(rh + xh) * 256))[lane];
                acc4(acc, u00, w00);
                acc4(acc, u01, w01);
                acc4(acc, u10, w10);
                acc4(acc, u11, w11);
            }
        }
        acc.x *= 0.25f; acc.y *= 0.25f; acc.z *= 0.25f; acc.w *= 0.25f;
        *(float4*)&lds[(cell - CB) * 260 + 4 * lane] = acc;   // ds_write_b128, 2-way max
    }
    __syncthreads();

    if (g == 0) store_out<28, 0>(lds, out, n);
    else        store_out<21, 28>(lds, out, n);
}

// ---------------- fallback: direct gather (if ws too small) ----------------
__global__ __launch_bounds__(256) void roi_direct(
    const float* __restrict__ f0, const float* __restrict__ f1,
    const float* __restrict__ f2, const float* __restrict__ f3,
    const float* __restrict__ boxes, float* __restrict__ out)
{
    const int total = B_ * R_ * C_ * OUTSZ * OUTSZ;
    int idx = blockIdx.x * blockDim.x + threadIdx.x;
    if (idx >= total) return;
    int ox = idx % 7, oy = (idx / 7) % 7, c = (idx / 49) % C_, n = idx / (49 * C_), b = n >> 8;
    const float* bx = boxes + (size_t)n * 4;
    float x1 = bx[0], y1 = bx[1], x2 = bx[2], y2 = bx[3];
    float lf = floorf(4.0f + log2f(sqrtf((x2 - x1) * (y2 - y1)) / 224.0f + 1e-8f));
    int lvl = (int)fminf(fmaxf(lf, 2.0f), 5.0f) - 2;
    const float scales[4] = {0.25f, 0.125f, 0.0625f, 0.03125f};
    const int sizes[4] = {200, 100, 50, 25};
    float scale = scales[lvl]; int HW = sizes[lvl];
    const float* fl = lvl == 0 ? f0 : lvl == 1 ? f1 : lvl == 2 ? f2 : f3;
    float fx1 = x1 * scale, fy1 = y1 * scale;
    float bw = fmaxf(x2 * scale - fx1, 1.0f) / 7.0f, bh = fmaxf(y2 * scale - fy1, 1.0f) / 7.0f;
    const float* plane = fl + ((size_t)(b * C_ + c)) * HW * HW;
    float lim = (float)HW, cap = lim - 1.0f, acc = 0.0f;
    #pragma unroll
    for (int sy = 0; sy < 2; sy++) {
        float yc = fy1 + bh * ((float)oy + ((float)sy + 0.5f) * 0.5f);
        bool vy = (yc > -1.0f) && (yc < lim);
        float ccy = fmaxf(yc, 0.0f), lowy = floorf(ccy);
        bool ey = lowy >= cap; lowy = fminf(lowy, cap);
        float highy = fminf(lowy + 1.0f, cap);
        float wfy = ey ? 0.0f : (ccy - lowy);
        int yl = (int)lowy, yh = (int)highy;
        #pragma unroll
        for (int sx = 0; sx < 2; sx++) {
            float xc = fx1 + bw * ((float)ox + ((float)sx + 0.5f) * 0.5f);
            bool vx = (xc > -1.0f) && (xc < lim);
            float ccx = fmaxf(xc, 0.0f), lowx = floorf(ccx);
            bool ex = lowx >= cap; lowx = fminf(lowx, cap);
            float highx = fminf(lowx + 1.0f, cap);
            float wfx = ex ? 0.0f : (ccx - lowx);
            int xl = (int)lowx, xh = (int)highx;
            if (vy && vx) {
                float v00 = plane[yl * HW + xl], v01 = plane[yl * HW + xh];
                float v10 = plane[yh * HW + xl], v11 = plane[yh * HW + xh];
                acc += (1.0f - wfy) * ((1.0f - wfx) * v00 + wfx * v01)
                     + wfy * ((1.0f - wfx) * v10 + wfx * v11);
            }
        }
    }
    out[idx] = acc * 0.25f;
}

extern "C" void kernel_launch(void* const* d_in, const int* in_sizes, int n_in,
                              void* d_out, int out_size, void* d_ws, size_t ws_size,
                              hipStream_t stream) {
    const float* f0    = (const float*)d_in[0];
    const float* f1    = (const float*)d_in[1];
    const float* f2    = (const float*)d_in[2];
    const float* f3    = (const float*)d_in[3];
    const float* boxes = (const float*)d_in[4];
    float* out = (float*)d_out;

    if (ws_size < WS_NEEDED) {
        const int total = B_ * R_ * C_ * OUTSZ * OUTSZ;
        roi_direct<<<(total + 255) / 256, 256, 0, stream>>>(f0, f1, f2, f3, boxes, out);
        return;
    }

    u16* nhwc = (u16*)d_ws;

    nhwc_cast<<<dim3(210, 4, 2), 256, 0, stream>>>(f0, f1, f2, f3, nhwc);
    roi_gather<<<dim3(2, N_), 256, 0, stream>>>(nhwc, boxes, out);
}

// Round 5
// 180.793 us; speedup vs baseline: 1.1385x; 1.1385x over previous
//
#include <hip/hip_runtime.h>
#include <math.h>

typedef unsigned short u16;
typedef unsigned int   u32;

#define OUTSZ 7
#define B_ 2
#define C_ 256
#define R_ 256
#define N_ (B_ * R_)

// NHWC bf16 scratch: pixel index -> 256 bf16 channels (512B records).
// per-batch level pixel bases: L0:0 L1:80000 L2:100000 L3:105000 (b-major within level)
#define PX_TOTAL 106250
#define WS_NEEDED ((size_t)PX_TOTAL * 256 * 2)

__device__ __forceinline__ u16 f2bf(float v) {
    u32 u = __float_as_uint(v);
    u += 0x7fffu + ((u >> 16) & 1u);           // RNE to bf16
    return (u16)(u >> 16);
}

__device__ __forceinline__ u32 pack2bf(float a, float b) {
    return (u32)f2bf(a) | ((u32)f2bf(b) << 16);
}

// ---------------- NCHW fp32 -> NHWC bf16: reg pack + 32KB swizzled LDS ----------
// 512 threads (8 waves); wave owns 8 consecutive channels -> staging is only
// f[8][4] = 32 VGPRs (structurally low reg need -> 8 waves/SIMD, 4 resident
// blocks = 32 waves/CU). Each thread: 8 float4 row loads in flight, packs
// bf16 uint4 in registers, writes px-major swizzled LDS (q = wave ^ (lane&7),
// consecutive 8 lanes cover all 8 bank-quads -> conflict-free b128), then
// block stores full 128B-line segments (8 lanes x 16B per pixel record).
// grid = (210 px-tiles, 4 ch-blocks, 2 batches), block 512.
__global__ __launch_bounds__(512, 8) void nhwc_cast(
    const float* __restrict__ f0, const float* __restrict__ f1,
    const float* __restrict__ f2, const float* __restrict__ f3,
    u16* __restrict__ dst)
{
    __shared__ u32 lds32[256 * 32];   // 32 KB: px-major, 8 uint4-quads per px, swizzled
    const int tid  = threadIdx.x;
    const int lane = tid & 63;
    const int wave = tid >> 6;        // 0..7

    const int t  = blockIdx.x;
    const int cb = blockIdx.y;
    const int b  = blockIdx.z;
    const float* src; int HWsz, dstBase, ft;
    if      (t < 157) { src = f0; HWsz = 40000; dstBase = 0;      ft = t;       }
    else if (t < 197) { src = f1; HWsz = 10000; dstBase = 80000;  ft = t - 157; }
    else if (t < 207) { src = f2; HWsz = 2500;  dstBase = 100000; ft = t - 197; }
    else              { src = f3; HWsz = 625;   dstBase = 105000; ft = t - 207; }

    const int fbase = ft * 256;
    const int cw    = cb * 64 + wave * 8;        // this wave's 8-channel base
    const int rem   = HWsz - fbase;              // >= 1
    const int p0    = 4 * lane;
    const bool vec  = ((HWsz & 3) == 0) && (p0 + 3 < rem);

    const float* base = src + ((size_t)(b * C_ + cw)) * HWsz + fbase;

    // 1) all 8 row loads in flight
    float f[8][4];
    #pragma unroll
    for (int i = 0; i < 8; ++i) {
        const float* row = base + (size_t)i * HWsz;
        if (vec) {
            float4 v = *(const float4*)(row + p0);
            f[i][0] = v.x; f[i][1] = v.y; f[i][2] = v.z; f[i][3] = v.w;
        } else {
            #pragma unroll
            for (int k = 0; k < 4; ++k)
                f[i][k] = (p0 + k < rem) ? row[p0 + k] : 0.0f;
        }
    }

    // 2) pack + swizzled LDS write: logical quad (channel octet) = wave,
    //    physical quad = wave ^ ((px>>2)&7) = wave ^ (lane&7)
    #pragma unroll
    for (int j = 0; j < 4; ++j) {
        uint4 o;
        o.x = pack2bf(f[0][j], f[1][j]);
        o.y = pack2bf(f[2][j], f[3][j]);
        o.z = pack2bf(f[4][j], f[5][j]);
        o.w = pack2bf(f[6][j], f[7][j]);
        const int q = wave ^ (lane & 7);
        *(uint4*)&lds32[(p0 + j) * 32 + q * 4] = o;
    }
    __syncthreads();

    // 3) full-line stores: thread (px,sub) reads swizzled quad, stores 16B;
    //    8 lanes/px -> 128B contiguous, wave -> 1KB contiguous
    const int maxpx = rem < 256 ? rem : 256;
    #pragma unroll
    for (int i = 0; i < 4; ++i) {
        const int idx = i * 512 + tid;
        const int px  = idx >> 3;
        const int sub = idx & 7;
        if (px < maxpx) {
            const int q = sub ^ ((px >> 2) & 7);
            uint4 o = *(const uint4*)&lds32[px * 32 + q * 4];
            *(uint4*)(dst + (size_t)(dstBase + b * HWsz + fbase + px) * 256 + cb * 64 + sub * 8) = o;
        }
    }
}

// ---------------- gather: block owns (ROI n, 128 channels); prep fused in-block ----
// Round-2 proven body: u32-per-lane record loads, LDS-staged output, block
// writes one contiguous 25KB slab as full-line float4s. Bilinear tables
// computed by threads 0..27 (prep kernel fused away).
__global__ __launch_bounds__(256) void roi_gather(
    const u16* __restrict__ ws16, const float* __restrict__ boxes,
    float* __restrict__ out)
{
    __shared__ float lds[128 * 49];            // 25088 B
    __shared__ float s_wy0[14], s_wy1[14], s_wx0[14], s_wx1[14];
    __shared__ int   s_yl[14], s_yh[14], s_xl[14], s_xh[14];
    __shared__ int   s_base, s_W;

    const int g    = blockIdx.x;
    const int n    = blockIdx.y;
    const int tid  = threadIdx.x;
    const int lane = tid & 63;
    const int wave = tid >> 6;

    // ---- fused prep: threads 0..13 -> y entries, 14..27 -> x entries ----
    if (tid < 28) {
        const float* bx = boxes + (size_t)n * 4;
        float x1 = bx[0], y1 = bx[1], x2 = bx[2], y2 = bx[3];
        float area = (x2 - x1) * (y2 - y1);
        float lf = floorf(4.0f + log2f(sqrtf(area) / 224.0f + 1e-8f));
        lf = fminf(fmaxf(lf, 2.0f), 5.0f);
        int lvl = (int)lf - 2;
        const float scales[4] = {0.25f, 0.125f, 0.0625f, 0.03125f};
        const int   sizes[4]  = {200, 100, 50, 25};
        const int   bases[4]  = {0, 80000, 100000, 105000};
        float scale = scales[lvl];
        int   HW    = sizes[lvl];
        float lim = (float)HW, cap = lim - 1.0f;
        float fx1 = x1 * scale, fy1 = y1 * scale;
        float bw = fmaxf(x2 * scale - fx1, 1.0f) / (float)OUTSZ;
        float bh = fmaxf(y2 * scale - fy1, 1.0f) / (float)OUTSZ;
        if (tid == 0) { s_base = bases[lvl] + (n >> 8) * HW * HW; s_W = HW; }

        const int  i   = (tid < 14) ? tid : tid - 14;
        const bool isy = tid < 14;
        float o  = isy ? fy1 : fx1;
        float st = isy ? bh  : bw;
        float gq = (float)(i >> 1) + ((float)(i & 1) + 0.5f) * 0.5f;
        float c = o + st * gq;
        bool  v = (c > -1.0f) && (c < lim);
        float cc = fmaxf(c, 0.0f);
        float low = floorf(cc);
        bool  edge = low >= cap;
        low = fminf(low, cap);
        float high = fminf(low + 1.0f, cap);
        float fr = edge ? 0.0f : (cc - low);
        float w0 = v ? (1.0f - fr) : 0.0f;
        float w1 = v ? fr : 0.0f;
        if (isy) { s_yl[i] = (int)low; s_yh[i] = (int)high; s_wy0[i] = w0; s_wy1[i] = w1; }
        else     { s_xl[i] = (int)low; s_xh[i] = (int)high; s_wx0[i] = w0; s_wx1[i] = w1; }
    }
    __syncthreads();

    const int base = s_base, W = s_W;
    const int c0 = g * 128;

    for (int cell = wave; cell < 49; cell += 4) {
        const int cu = __builtin_amdgcn_readfirstlane(cell);
        const int oy = cu / 7, ox = cu - oy * 7;
        float a0 = 0.0f, a1 = 0.0f;
        #pragma unroll
        for (int sy = 0; sy < 2; ++sy) {
            const int ei = oy * 2 + sy;
            const float wy0 = s_wy0[ei], wy1 = s_wy1[ei];
            const int rl = base + s_yl[ei] * W;
            const int rh = base + s_yh[ei] * W;
            #pragma unroll
            for (int sx = 0; sx < 2; ++sx) {
                const int ej = ox * 2 + sx;
                const float w00 = wy0 * s_wx0[ej], w01 = wy0 * s_wx1[ej];
                const float w10 = wy1 * s_wx0[ej], w11 = wy1 * s_wx1[ej];
                const int xl = s_xl[ej], xh = s_xh[ej];
                u32 u00 = ((const u32*)(ws16 + (size_t)(rl + xl) * 256 + c0))[lane];
                u32 u01 = ((const u32*)(ws16 + (size_t)(rl + xh) * 256 + c0))[lane];
                u32 u10 = ((const u32*)(ws16 + (size_t)(rh + xl) * 256 + c0))[lane];
                u32 u11 = ((const u32*)(ws16 + (size_t)(rh + xh) * 256 + c0))[lane];
                a0 += w00 * __uint_as_float(u00 << 16) + w01 * __uint_as_float(u01 << 16)
                    + w10 * __uint_as_float(u10 << 16) + w11 * __uint_as_float(u11 << 16);
                a1 += w00 * __uint_as_float(u00 & 0xffff0000u) + w01 * __uint_as_float(u01 & 0xffff0000u)
                    + w10 * __uint_as_float(u10 & 0xffff0000u) + w11 * __uint_as_float(u11 & 0xffff0000u);
            }
        }
        lds[(2 * lane) * 49 + cu]     = a0 * 0.25f;
        lds[(2 * lane + 1) * 49 + cu] = a1 * 0.25f;
    }
    __syncthreads();

    const float4* lv = (const float4*)lds;
    float4* ov = (float4*)(out + ((size_t)(n * C_ + c0)) * 49);
    for (int i = tid; i < 1568; i += 256) ov[i] = lv[i];
}

// ---------------- fallback: direct gather (if ws too small) ----------------
__global__ __launch_bounds__(256) void roi_direct(
    const float* __restrict__ f0, const float* __restrict__ f1,
    const float* __restrict__ f2, const float* __restrict__ f3,
    const float* __restrict__ boxes, float* __restrict__ out)
{
    const int total = B_ * R_ * C_ * OUTSZ * OUTSZ;
    int idx = blockIdx.x * blockDim.x + threadIdx.x;
    if (idx >= total) return;
    int ox = idx % 7, oy = (idx / 7) % 7, c = (idx / 49) % C_, n = idx / (49 * C_), b = n >> 8;
    const float* bx = boxes + (size_t)n * 4;
    float x1 = bx[0], y1 = bx[1], x2 = bx[2], y2 = bx[3];
    float lf = floorf(4.0f + log2f(sqrtf((x2 - x1) * (y2 - y1)) / 224.0f + 1e-8f));
    int lvl = (int)fminf(fmaxf(lf, 2.0f), 5.0f) - 2;
    const float scales[4] = {0.25f, 0.125f, 0.0625f, 0.03125f};
    const int sizes[4] = {200, 100, 50, 25};
    float scale = scales[lvl]; int HW = sizes[lvl];
    const float* fl = lvl == 0 ? f0 : lvl == 1 ? f1 : lvl == 2 ? f2 : f3;
    float fx1 = x1 * scale, fy1 = y1 * scale;
    float bw = fmaxf(x2 * scale - fx1, 1.0f) / 7.0f, bh = fmaxf(y2 * scale - fy1, 1.0f) / 7.0f;
    const float* plane = fl + ((size_t)(b * C_ + c)) * HW * HW;
    float lim = (float)HW, cap = lim - 1.0f, acc = 0.0f;
    #pragma unroll
    for (int sy = 0; sy < 2; sy++) {
        float yc = fy1 + bh * ((float)oy + ((float)sy + 0.5f) * 0.5f);
        bool vy = (yc > -1.0f) && (yc < lim);
        float ccy = fmaxf(yc, 0.0f), lowy = floorf(ccy);
        bool ey = lowy >= cap; lowy = fminf(lowy, cap);
        float highy = fminf(lowy + 1.0f, cap);
        float wfy = ey ? 0.0f : (ccy - lowy);
        int yl = (int)lowy, yh = (int)highy;
        #pragma unroll
        for (int sx = 0; sx < 2; sx++) {
            float xc = fx1 + bw * ((float)ox + ((float)sx + 0.5f) * 0.5f);
            bool vx = (xc > -1.0f) && (xc < lim);
            float ccx = fmaxf(xc, 0.0f), lowx = floorf(ccx);
            bool ex = lowx >= cap; lowx = fminf(lowx, cap);
            float highx = fminf(lowx + 1.0f, cap);
            float wfx = ex ? 0.0f : (ccx - lowx);
            int xl = (int)lowx, xh = (int)highx;
            if (vy && vx) {
                float v00 = plane[yl * HW + xl], v01 = plane[yl * HW + xh];
                float v10 = plane[yh * HW + xl], v11 = plane[yh * HW + xh];
                acc += (1.0f - wfy) * ((1.0f - wfx) * v00 + wfx * v01)
                     + wfy * ((1.0f - wfx) * v10 + wfx * v11);
            }
        }
    }
    out[idx] = acc * 0.25f;
}

extern "C" void kernel_launch(void* const* d_in, const int* in_sizes, int n_in,
                              void* d_out, int out_size, void* d_ws, size_t ws_size,
                              hipStream_t stream) {
    const float* f0    = (const float*)d_in[0];
    const float* f1    = (const float*)d_in[1];
    const float* f2    = (const float*)d_in[2];
    const float* f3    = (const float*)d_in[3];
    const float* boxes = (const float*)d_in[4];
    float* out = (float*)d_out;

    if (ws_size < WS_NEEDED) {
        const int total = B_ * R_ * C_ * OUTSZ * OUTSZ;
        roi_direct<<<(total + 255) / 256, 256, 0, stream>>>(f0, f1, f2, f3, boxes, out);
        return;
    }

    u16* nhwc = (u16*)d_ws;

    nhwc_cast<<<dim3(210, 4, 2), 512, 0, stream>>>(f0, f1, f2, f3, nhwc);
    roi_gather<<<dim3(2, N_), 256, 0, stream>>>(nhwc, boxes, out);
}

// Round 6
// 177.899 us; speedup vs baseline: 1.1570x; 1.0163x over previous
//
#include <hip/hip_runtime.h>
#include <math.h>

typedef unsigned short u16;
typedef unsigned int   u32;

#define OUTSZ 7
#define B_ 2
#define C_ 256
#define R_ 256
#define N_ (B_ * R_)

// NHWC bf16 scratch: pixel index -> 256 bf16 channels (512B records).
// per-batch level pixel bases: L0:0 L1:80000 L2:100000 L3:105000 (b-major within level)
#define PX_TOTAL 106250
#define WS_NEEDED ((size_t)PX_TOTAL * 256 * 2)

__device__ __forceinline__ u16 f2bf(float v) {
    u32 u = __float_as_uint(v);
    u += 0x7fffu + ((u >> 16) & 1u);           // RNE to bf16
    return (u16)(u >> 16);
}

__device__ __forceinline__ u32 pack2bf(float a, float b) {
    return (u32)f2bf(a) | ((u32)f2bf(b) << 16);
}

// ---------------- NCHW fp32 -> NHWC bf16: reg pack + 32KB swizzled LDS ----------
// 512 threads (8 waves); wave owns 8 consecutive channels. Each thread: 8
// float4 row loads; sched_barrier(0) pins ALL 8 loads before the pack phase
// (round-5 showed the compiler otherwise minimizes to VGPR=24 with only ~2
// loads in flight -> latency-bound at 2.1 TB/s). Pack bf16 uint4 in regs,
// write px-major swizzled LDS (q = wave ^ (lane&7), conflict-free b128),
// store full 128B-line segments (8 lanes x 16B per pixel record).
// grid = (210 px-tiles, 4 ch-blocks, 2 batches), block 512.
__global__ __launch_bounds__(512, 8) void nhwc_cast(
    const float* __restrict__ f0, const float* __restrict__ f1,
    const float* __restrict__ f2, const float* __restrict__ f3,
    u16* __restrict__ dst)
{
    __shared__ u32 lds32[256 * 32];   // 32 KB: px-major, 8 uint4-quads per px, swizzled
    const int tid  = threadIdx.x;
    const int lane = tid & 63;
    const int wave = tid >> 6;        // 0..7

    const int t  = blockIdx.x;
    const int cb = blockIdx.y;
    const int b  = blockIdx.z;
    const float* src; int HWsz, dstBase, ft;
    if      (t < 157) { src = f0; HWsz = 40000; dstBase = 0;      ft = t;       }
    else if (t < 197) { src = f1; HWsz = 10000; dstBase = 80000;  ft = t - 157; }
    else if (t < 207) { src = f2; HWsz = 2500;  dstBase = 100000; ft = t - 197; }
    else              { src = f3; HWsz = 625;   dstBase = 105000; ft = t - 207; }

    const int fbase = ft * 256;
    const int cw    = cb * 64 + wave * 8;        // this wave's 8-channel base
    const int rem   = HWsz - fbase;              // >= 1
    const int p0    = 4 * lane;
    const bool vec  = ((HWsz & 3) == 0) && (p0 + 3 < rem);

    const float* base = src + ((size_t)(b * C_ + cw)) * HWsz + fbase;

    // 1) all 8 row loads issued before any pack (sched_barrier pins this)
    float f[8][4];
    #pragma unroll
    for (int i = 0; i < 8; ++i) {
        const float* row = base + (size_t)i * HWsz;
        if (vec) {
            float4 v = *(const float4*)(row + p0);
            f[i][0] = v.x; f[i][1] = v.y; f[i][2] = v.z; f[i][3] = v.w;
        } else {
            #pragma unroll
            for (int k = 0; k < 4; ++k)
                f[i][k] = (p0 + k < rem) ? row[p0 + k] : 0.0f;
        }
    }
    __builtin_amdgcn_sched_barrier(0);   // keep all 8 loads in flight (MLP)

    // 2) pack + swizzled LDS write: logical quad (channel octet) = wave,
    //    physical quad = wave ^ ((px>>2)&7) = wave ^ (lane&7)
    #pragma unroll
    for (int j = 0; j < 4; ++j) {
        uint4 o;
        o.x = pack2bf(f[0][j], f[1][j]);
        o.y = pack2bf(f[2][j], f[3][j]);
        o.z = pack2bf(f[4][j], f[5][j]);
        o.w = pack2bf(f[6][j], f[7][j]);
        const int q = wave ^ (lane & 7);
        *(uint4*)&lds32[(p0 + j) * 32 + q * 4] = o;
    }
    __syncthreads();

    // 3) full-line stores: thread (px,sub) reads swizzled quad, stores 16B;
    //    8 lanes/px -> 128B contiguous, wave -> 1KB contiguous
    const int maxpx = rem < 256 ? rem : 256;
    #pragma unroll
    for (int i = 0; i < 4; ++i) {
        const int idx = i * 512 + tid;
        const int px  = idx >> 3;
        const int sub = idx & 7;
        if (px < maxpx) {
            const int q = sub ^ ((px >> 2) & 7);
            uint4 o = *(const uint4*)&lds32[px * 32 + q * 4];
            *(uint4*)(dst + (size_t)(dstBase + b * HWsz + fbase + px) * 256 + cb * 64 + sub * 8) = o;
        }
    }
}

// ---------------- gather: block owns (ROI n, 128 channels); prep fused in-block ----
// Round-2 proven body, now 512 threads / 8 waves: cells strided by 8 ->
// 4 resident blocks x 8 waves = 32 waves/CU (was 16). u32-per-lane record
// loads, LDS-staged output, block writes one contiguous 25KB slab as
// full-line float4s. Bilinear tables computed by threads 0..27.
__global__ __launch_bounds__(512, 8) void roi_gather(
    const u16* __restrict__ ws16, const float* __restrict__ boxes,
    float* __restrict__ out)
{
    __shared__ float lds[128 * 49];            // 25088 B
    __shared__ float s_wy0[14], s_wy1[14], s_wx0[14], s_wx1[14];
    __shared__ int   s_yl[14], s_yh[14], s_xl[14], s_xh[14];
    __shared__ int   s_base, s_W;

    const int g    = blockIdx.x;
    const int n    = blockIdx.y;
    const int tid  = threadIdx.x;
    const int lane = tid & 63;
    const int wave = tid >> 6;     // 0..7

    // ---- fused prep: threads 0..13 -> y entries, 14..27 -> x entries ----
    if (tid < 28) {
        const float* bx = boxes + (size_t)n * 4;
        float x1 = bx[0], y1 = bx[1], x2 = bx[2], y2 = bx[3];
        float area = (x2 - x1) * (y2 - y1);
        float lf = floorf(4.0f + log2f(sqrtf(area) / 224.0f + 1e-8f));
        lf = fminf(fmaxf(lf, 2.0f), 5.0f);
        int lvl = (int)lf - 2;
        const float scales[4] = {0.25f, 0.125f, 0.0625f, 0.03125f};
        const int   sizes[4]  = {200, 100, 50, 25};
        const int   bases[4]  = {0, 80000, 100000, 105000};
        float scale = scales[lvl];
        int   HW    = sizes[lvl];
        float lim = (float)HW, cap = lim - 1.0f;
        float fx1 = x1 * scale, fy1 = y1 * scale;
        float bw = fmaxf(x2 * scale - fx1, 1.0f) / (float)OUTSZ;
        float bh = fmaxf(y2 * scale - fy1, 1.0f) / (float)OUTSZ;
        if (tid == 0) { s_base = bases[lvl] + (n >> 8) * HW * HW; s_W = HW; }

        const int  i   = (tid < 14) ? tid : tid - 14;
        const bool isy = tid < 14;
        float o  = isy ? fy1 : fx1;
        float st = isy ? bh  : bw;
        float gq = (float)(i >> 1) + ((float)(i & 1) + 0.5f) * 0.5f;
        float c = o + st * gq;
        bool  v = (c > -1.0f) && (c < lim);
        float cc = fmaxf(c, 0.0f);
        float low = floorf(cc);
        bool  edge = low >= cap;
        low = fminf(low, cap);
        float high = fminf(low + 1.0f, cap);
        float fr = edge ? 0.0f : (cc - low);
        float w0 = v ? (1.0f - fr) : 0.0f;
        float w1 = v ? fr : 0.0f;
        if (isy) { s_yl[i] = (int)low; s_yh[i] = (int)high; s_wy0[i] = w0; s_wy1[i] = w1; }
        else     { s_xl[i] = (int)low; s_xh[i] = (int)high; s_wx0[i] = w0; s_wx1[i] = w1; }
    }
    __syncthreads();

    const int base = s_base, W = s_W;
    const int c0 = g * 128;

    for (int cell = wave; cell < 49; cell += 8) {
        const int cu = __builtin_amdgcn_readfirstlane(cell);
        const int oy = cu / 7, ox = cu - oy * 7;
        float a0 = 0.0f, a1 = 0.0f;
        #pragma unroll
        for (int sy = 0; sy < 2; ++sy) {
            const int ei = oy * 2 + sy;
            const float wy0 = s_wy0[ei], wy1 = s_wy1[ei];
            const int rl = base + s_yl[ei] * W;
            const int rh = base + s_yh[ei] * W;
            #pragma unroll
            for (int sx = 0; sx < 2; ++sx) {
                const int ej = ox * 2 + sx;
                const float w00 = wy0 * s_wx0[ej], w01 = wy0 * s_wx1[ej];
                const float w10 = wy1 * s_wx0[ej], w11 = wy1 * s_wx1[ej];
                const int xl = s_xl[ej], xh = s_xh[ej];
                u32 u00 = ((const u32*)(ws16 + (size_t)(rl + xl) * 256 + c0))[lane];
                u32 u01 = ((const u32*)(ws16 + (size_t)(rl + xh) * 256 + c0))[lane];
                u32 u10 = ((const u32*)(ws16 + (size_t)(rh + xl) * 256 + c0))[lane];
                u32 u11 = ((const u32*)(ws16 + (size_t)(rh + xh) * 256 + c0))[lane];
                a0 += w00 * __uint_as_float(u00 << 16) + w01 * __uint_as_float(u01 << 16)
                    + w10 * __uint_as_float(u10 << 16) + w11 * __uint_as_float(u11 << 16);
                a1 += w00 * __uint_as_float(u00 & 0xffff0000u) + w01 * __uint_as_float(u01 & 0xffff0000u)
                    + w10 * __uint_as_float(u10 & 0xffff0000u) + w11 * __uint_as_float(u11 & 0xffff0000u);
            }
        }
        lds[(2 * lane) * 49 + cu]     = a0 * 0.25f;
        lds[(2 * lane + 1) * 49 + cu] = a1 * 0.25f;
    }
    __syncthreads();

    const float4* lv = (const float4*)lds;
    float4* ov = (float4*)(out + ((size_t)(n * C_ + c0)) * 49);
    for (int i = tid; i < 1568; i += 512) ov[i] = lv[i];
}

// ---------------- fallback: direct gather (if ws too small) ----------------
__global__ __launch_bounds__(256) void roi_direct(
    const float* __restrict__ f0, const float* __restrict__ f1,
    const float* __restrict__ f2, const float* __restrict__ f3,
    const float* __restrict__ boxes, float* __restrict__ out)
{
    const int total = B_ * R_ * C_ * OUTSZ * OUTSZ;
    int idx = blockIdx.x * blockDim.x + threadIdx.x;
    if (idx >= total) return;
    int ox = idx % 7, oy = (idx / 7) % 7, c = (idx / 49) % C_, n = idx / (49 * C_), b = n >> 8;
    const float* bx = boxes + (size_t)n * 4;
    float x1 = bx[0], y1 = bx[1], x2 = bx[2], y2 = bx[3];
    float lf = floorf(4.0f + log2f(sqrtf((x2 - x1) * (y2 - y1)) / 224.0f + 1e-8f));
    int lvl = (int)fminf(fmaxf(lf, 2.0f), 5.0f) - 2;
    const float scales[4] = {0.25f, 0.125f, 0.0625f, 0.03125f};
    const int sizes[4] = {200, 100, 50, 25};
    float scale = scales[lvl]; int HW = sizes[lvl];
    const float* fl = lvl == 0 ? f0 : lvl == 1 ? f1 : lvl == 2 ? f2 : f3;
    float fx1 = x1 * scale, fy1 = y1 * scale;
    float bw = fmaxf(x2 * scale - fx1, 1.0f) / 7.0f, bh = fmaxf(y2 * scale - fy1, 1.0f) / 7.0f;
    const float* plane = fl + ((size_t)(b * C_ + c)) * HW * HW;
    float lim = (float)HW, cap = lim - 1.0f, acc = 0.0f;
    #pragma unroll
    for (int sy = 0; sy < 2; sy++) {
        float yc = fy1 + bh * ((float)oy + ((float)sy + 0.5f) * 0.5f);
        bool vy = (yc > -1.0f) && (yc < lim);
        float ccy = fmaxf(yc, 0.0f), lowy = floorf(ccy);
        bool ey = lowy >= cap; lowy = fminf(lowy, cap);
        float highy = fminf(lowy + 1.0f, cap);
        float wfy = ey ? 0.0f : (ccy - lowy);
        int yl = (int)lowy, yh = (int)highy;
        #pragma unroll
        for (int sx = 0; sx < 2; sx++) {
            float xc = fx1 + bw * ((float)ox + ((float)sx + 0.5f) * 0.5f);
            bool vx = (xc > -1.0f) && (xc < lim);
            float ccx = fmaxf(xc, 0.0f), lowx = floorf(ccx);
            bool ex = lowx >= cap; lowx = fminf(lowx, cap);
            float highx = fminf(lowx + 1.0f, cap);
            float wfx = ex ? 0.0f : (ccx - lowx);
            int xl = (int)lowx, xh = (int)highx;
            if (vy && vx) {
                float v00 = plane[yl * HW + xl], v01 = plane[yl * HW + xh];
                float v10 = plane[yh * HW + xl], v11 = plane[yh * HW + xh];
                acc += (1.0f - wfy) * ((1.0f - wfx) * v00 + wfx * v01)
                     + wfy * ((1.0f - wfx) * v10 + wfx * v11);
            }
        }
    }
    out[idx] = acc * 0.25f;
}

extern "C" void kernel_launch(void* const* d_in, const int* in_sizes, int n_in,
                              void* d_out, int out_size, void* d_ws, size_t ws_size,
                              hipStream_t stream) {
    const float* f0    = (const float*)d_in[0];
    const float* f1    = (const float*)d_in[1];
    const float* f2    = (const float*)d_in[2];
    const float* f3    = (const float*)d_in[3];
    const float* boxes = (const float*)d_in[4];
    float* out = (float*)d_out;

    if (ws_size < WS_NEEDED) {
        const int total = B_ * R_ * C_ * OUTSZ * OUTSZ;
        roi_direct<<<(total + 255) / 256, 256, 0, stream>>>(f0, f1, f2, f3, boxes, out);
        return;
    }

    u16* nhwc = (u16*)d_ws;

    nhwc_cast<<<dim3(210, 4, 2), 512, 0, stream>>>(f0, f1, f2, f3, nhwc);
    roi_gather<<<dim3(2, N_), 512, 0, stream>>>(nhwc, boxes, out);
}

// Round 7
// 177.102 us; speedup vs baseline: 1.1622x; 1.0045x over previous
//
#include <hip/hip_runtime.h>
#include <math.h>

typedef unsigned short u16;
typedef unsigned int   u32;

#define OUTSZ 7
#define B_ 2
#define C_ 256
#define R_ 256
#define N_ (B_ * R_)

// NHWC bf16 scratch: pixel index -> 256 bf16 channels (512B records).
// per-batch level pixel bases: L0:0 L1:80000 L2:100000 L3:105000 (b-major within level)
#define PX_TOTAL 106250
#define WS_NEEDED ((size_t)PX_TOTAL * 256 * 2)

__device__ __forceinline__ u16 f2bf(float v) {
    u32 u = __float_as_uint(v);
    u += 0x7fffu + ((u >> 16) & 1u);           // RNE to bf16
    return (u16)(u >> 16);
}

__device__ __forceinline__ u32 pack2bf(float a, float b) {
    return (u32)f2bf(a) | ((u32)f2bf(b) << 16);
}

// ---------------- NCHW fp32 -> NHWC bf16: global_load_lds DMA staging ----------
// R6 lesson: VGPR-staged loads serialize (compiler hoists cvt into the load
// loop; dest-reg hazards cap MLP at ~1-2, VGPR=24, BW stuck at 2.1 TB/s).
// Fix: stage fp32 via __builtin_amdgcn_global_load_lds (no VGPR round-trip,
// vmcnt-counted, hazard-free). Per 64ch x 256px tile, two 128-px phases:
//   stage: 32 DMA instrs (4/wave), per-lane global addr covers a channel
//          PAIR per instr (lanes 0-31 = ch 2p, 32-63 = ch 2p+1), LDS dest
//          linear: pair p at float-offset p*260 (1040B padded pairs).
//   consume: thread (pxl,sub) reads 8 fp32 (ds_read_b32, <=4-way conflict),
//          packs bf16 uint4, stores full 128B-line segments (8 lanes/px).
// 33280B LDS -> 4 blocks/CU -> 32 waves/CU. Tail/odd tiles (~3%) use the
// proven register path. grid = (210, 4, 2), block 512.
__global__ __launch_bounds__(512, 8) void nhwc_cast(
    const float* __restrict__ f0, const float* __restrict__ f1,
    const float* __restrict__ f2, const float* __restrict__ f3,
    u16* __restrict__ dst)
{
    __shared__ float smemf[32 * 260];   // 33280 B (reg path reuses as u32[256*32])
    const int tid  = threadIdx.x;
    const int lane = tid & 63;
    const int wave = tid >> 6;          // 0..7

    const int t  = blockIdx.x;
    const int cb = blockIdx.y;
    const int b  = blockIdx.z;
    const float* src; int HWsz, dstBase, ft;
    if      (t < 157) { src = f0; HWsz = 40000; dstBase = 0;      ft = t;       }
    else if (t < 197) { src = f1; HWsz = 10000; dstBase = 80000;  ft = t - 157; }
    else if (t < 207) { src = f2; HWsz = 2500;  dstBase = 100000; ft = t - 197; }
    else              { src = f3; HWsz = 625;   dstBase = 105000; ft = t - 207; }

    const int fbase = ft * 256;
    const int rem   = HWsz - fbase;              // >= 1
    const bool dma  = ((HWsz & 3) == 0) && (rem >= 256);

    if (dma) {
        const float* gb = src + (size_t)(b * C_ + cb * 64) * HWsz + fbase;
        #pragma unroll
        for (int h = 0; h < 2; ++h) {
            if (h) __syncthreads();              // LDS reads of phase 0 done
            // ---- stage: 4 DMA instrs per wave, ch-pair p = k*8 + wave ----
            #pragma unroll
            for (int k = 0; k < 4; ++k) {
                const int p = k * 8 + wave;
                const float* g = gb + (size_t)(2 * p + (lane >> 5)) * HWsz
                               + h * 128 + (lane & 31) * 4;
                __builtin_amdgcn_global_load_lds(
                    (const __attribute__((address_space(1))) void*)g,
                    (__attribute__((address_space(3))) void*)(smemf + p * 260),
                    16, 0, 0);
            }
            __syncthreads();                     // drains vmcnt + barrier
            // ---- consume: pack + full-line stores ----
            #pragma unroll
            for (int it = 0; it < 2; ++it) {
                const int idx = it * 512 + tid;
                const int pxl = idx >> 3;        // 0..127
                const int sub = idx & 7;         // 16B chunk (8 ch) within 128B line
                float v[8];
                #pragma unroll
                for (int k2 = 0; k2 < 8; ++k2) {
                    const int ch = sub * 8 + k2;
                    v[k2] = smemf[(ch >> 1) * 260 + (ch & 1) * 128 + pxl];
                }
                uint4 o;
                o.x = pack2bf(v[0], v[1]); o.y = pack2bf(v[2], v[3]);
                o.z = pack2bf(v[4], v[5]); o.w = pack2bf(v[6], v[7]);
                *(uint4*)(dst + (size_t)(dstBase + b * HWsz + fbase + h * 128 + pxl) * 256
                              + cb * 64 + sub * 8) = o;
            }
        }
    } else {
        // ---- proven register path for tail/odd tiles ----
        u32* lds32 = (u32*)smemf;                // px-major, 8 uint4-quads/px, swizzled
        const int cw = cb * 64 + wave * 8;
        const int p0 = 4 * lane;
        const float* base = src + ((size_t)(b * C_ + cw)) * HWsz + fbase;

        float f[8][4];
        #pragma unroll
        for (int i = 0; i < 8; ++i) {
            const float* row = base + (size_t)i * HWsz;
            #pragma unroll
            for (int k = 0; k < 4; ++k)
                f[i][k] = (p0 + k < rem) ? row[p0 + k] : 0.0f;
        }
        #pragma unroll
        for (int j = 0; j < 4; ++j) {
            uint4 o;
            o.x = pack2bf(f[0][j], f[1][j]);
            o.y = pack2bf(f[2][j], f[3][j]);
            o.z = pack2bf(f[4][j], f[5][j]);
            o.w = pack2bf(f[6][j], f[7][j]);
            const int q = wave ^ (lane & 7);     // ((px>>2)&7) == lane&7
            *(uint4*)&lds32[(p0 + j) * 32 + q * 4] = o;
        }
        __syncthreads();

        const int maxpx = rem < 256 ? rem : 256;
        #pragma unroll
        for (int i = 0; i < 4; ++i) {
            const int idx = i * 512 + tid;
            const int px  = idx >> 3;
            const int sub = idx & 7;
            if (px < maxpx) {
                const int q = sub ^ ((px >> 2) & 7);
                uint4 o = *(const uint4*)&lds32[px * 32 + q * 4];
                *(uint4*)(dst + (size_t)(dstBase + b * HWsz + fbase + px) * 256
                              + cb * 64 + sub * 8) = o;
            }
        }
    }
}

// ---------------- gather: block owns (ROI n, 128 channels); prep fused in-block ----
// 512 threads / 8 waves, cells strided by 8. u32-per-lane record loads,
// LDS-staged output, block writes one contiguous 25KB slab as full-line
// float4s. Bilinear tables computed by threads 0..27.
__global__ __launch_bounds__(512, 8) void roi_gather(
    const u16* __restrict__ ws16, const float* __restrict__ boxes,
    float* __restrict__ out)
{
    __shared__ float lds[128 * 49];            // 25088 B
    __shared__ float s_wy0[14], s_wy1[14], s_wx0[14], s_wx1[14];
    __shared__ int   s_yl[14], s_yh[14], s_xl[14], s_xh[14];
    __shared__ int   s_base, s_W;

    const int g    = blockIdx.x;
    const int n    = blockIdx.y;
    const int tid  = threadIdx.x;
    const int lane = tid & 63;
    const int wave = tid >> 6;     // 0..7

    // ---- fused prep: threads 0..13 -> y entries, 14..27 -> x entries ----
    if (tid < 28) {
        const float* bx = boxes + (size_t)n * 4;
        float x1 = bx[0], y1 = bx[1], x2 = bx[2], y2 = bx[3];
        float area = (x2 - x1) * (y2 - y1);
        float lf = floorf(4.0f + log2f(sqrtf(area) / 224.0f + 1e-8f));
        lf = fminf(fmaxf(lf, 2.0f), 5.0f);
        int lvl = (int)lf - 2;
        const float scales[4] = {0.25f, 0.125f, 0.0625f, 0.03125f};
        const int   sizes[4]  = {200, 100, 50, 25};
        const int   bases[4]  = {0, 80000, 100000, 105000};
        float scale = scales[lvl];
        int   HW    = sizes[lvl];
        float lim = (float)HW, cap = lim - 1.0f;
        float fx1 = x1 * scale, fy1 = y1 * scale;
        float bw = fmaxf(x2 * scale - fx1, 1.0f) / (float)OUTSZ;
        float bh = fmaxf(y2 * scale - fy1, 1.0f) / (float)OUTSZ;
        if (tid == 0) { s_base = bases[lvl] + (n >> 8) * HW * HW; s_W = HW; }

        const int  i   = (tid < 14) ? tid : tid - 14;
        const bool isy = tid < 14;
        float o  = isy ? fy1 : fx1;
        float st = isy ? bh  : bw;
        float gq = (float)(i >> 1) + ((float)(i & 1) + 0.5f) * 0.5f;
        float c = o + st * gq;
        bool  v = (c > -1.0f) && (c < lim);
        float cc = fmaxf(c, 0.0f);
        float low = floorf(cc);
        bool  edge = low >= cap;
        low = fminf(low, cap);
        float high = fminf(low + 1.0f, cap);
        float fr = edge ? 0.0f : (cc - low);
        float w0 = v ? (1.0f - fr) : 0.0f;
        float w1 = v ? fr : 0.0f;
        if (isy) { s_yl[i] = (int)low; s_yh[i] = (int)high; s_wy0[i] = w0; s_wy1[i] = w1; }
        else     { s_xl[i] = (int)low; s_xh[i] = (int)high; s_wx0[i] = w0; s_wx1[i] = w1; }
    }
    __syncthreads();

    const int base = s_base, W = s_W;
    const int c0 = g * 128;

    for (int cell = wave; cell < 49; cell += 8) {
        const int cu = __builtin_amdgcn_readfirstlane(cell);
        const int oy = cu / 7, ox = cu - oy * 7;
        float a0 = 0.0f, a1 = 0.0f;
        #pragma unroll
        for (int sy = 0; sy < 2; ++sy) {
            const int ei = oy * 2 + sy;
            const float wy0 = s_wy0[ei], wy1 = s_wy1[ei];
            const int rl = base + s_yl[ei] * W;
            const int rh = base + s_yh[ei] * W;
            #pragma unroll
            for (int sx = 0; sx < 2; ++sx) {
                const int ej = ox * 2 + sx;
                const float w00 = wy0 * s_wx0[ej], w01 = wy0 * s_wx1[ej];
                const float w10 = wy1 * s_wx0[ej], w11 = wy1 * s_wx1[ej];
                const int xl = s_xl[ej], xh = s_xh[ej];
                u32 u00 = ((const u32*)(ws16 + (size_t)(rl + xl) * 256 + c0))[lane];
                u32 u01 = ((const u32*)(ws16 + (size_t)(rl + xh) * 256 + c0))[lane];
                u32 u10 = ((const u32*)(ws16 + (size_t)(rh + xl) * 256 + c0))[lane];
                u32 u11 = ((const u32*)(ws16 + (size_t)(rh + xh) * 256 + c0))[lane];
                a0 += w00 * __uint_as_float(u00 << 16) + w01 * __uint_as_float(u01 << 16)
                    + w10 * __uint_as_float(u10 << 16) + w11 * __uint_as_float(u11 << 16);
                a1 += w00 * __uint_as_float(u00 & 0xffff0000u) + w01 * __uint_as_float(u01 & 0xffff0000u)
                    + w10 * __uint_as_float(u10 & 0xffff0000u) + w11 * __uint_as_float(u11 & 0xffff0000u);
            }
        }
        lds[(2 * lane) * 49 + cu]     = a0 * 0.25f;
        lds[(2 * lane + 1) * 49 + cu] = a1 * 0.25f;
    }
    __syncthreads();

    const float4* lv = (const float4*)lds;
    float4* ov = (float4*)(out + ((size_t)(n * C_ + c0)) * 49);
    for (int i = tid; i < 1568; i += 512) ov[i] = lv[i];
}

// ---------------- fallback: direct gather (if ws too small) ----------------
__global__ __launch_bounds__(256) void roi_direct(
    const float* __restrict__ f0, const float* __restrict__ f1,
    const float* __restrict__ f2, const float* __restrict__ f3,
    const float* __restrict__ boxes, float* __restrict__ out)
{
    const int total = B_ * R_ * C_ * OUTSZ * OUTSZ;
    int idx = blockIdx.x * blockDim.x + threadIdx.x;
    if (idx >= total) return;
    int ox = idx % 7, oy = (idx / 7) % 7, c = (idx / 49) % C_, n = idx / (49 * C_), b = n >> 8;
    const float* bx = boxes + (size_t)n * 4;
    float x1 = bx[0], y1 = bx[1], x2 = bx[2], y2 = bx[3];
    float lf = floorf(4.0f + log2f(sqrtf((x2 - x1) * (y2 - y1)) / 224.0f + 1e-8f));
    int lvl = (int)fminf(fmaxf(lf, 2.0f), 5.0f) - 2;
    const float scales[4] = {0.25f, 0.125f, 0.0625f, 0.03125f};
    const int sizes[4] = {200, 100, 50, 25};
    float scale = scales[lvl]; int HW = sizes[lvl];
    const float* fl = lvl == 0 ? f0 : lvl == 1 ? f1 : lvl == 2 ? f2 : f3;
    float fx1 = x1 * scale, fy1 = y1 * scale;
    float bw = fmaxf(x2 * scale - fx1, 1.0f) / 7.0f, bh = fmaxf(y2 * scale - fy1, 1.0f) / 7.0f;
    const float* plane = fl + ((size_t)(b * C_ + c)) * HW * HW;
    float lim = (float)HW, cap = lim - 1.0f, acc = 0.0f;
    #pragma unroll
    for (int sy = 0; sy < 2; sy++) {
        float yc = fy1 + bh * ((float)oy + ((float)sy + 0.5f) * 0.5f);
        bool vy = (yc > -1.0f) && (yc < lim);
        float ccy = fmaxf(yc, 0.0f), lowy = floorf(ccy);
        bool ey = lowy >= cap; lowy = fminf(lowy, cap);
        float highy = fminf(lowy + 1.0f, cap);
        float wfy = ey ? 0.0f : (ccy - lowy);
        int yl = (int)lowy, yh = (int)highy;
        #pragma unroll
        for (int sx = 0; sx < 2; sx++) {
            float xc = fx1 + bw * ((float)ox + ((float)sx + 0.5f) * 0.5f);
            bool vx = (xc > -1.0f) && (xc < lim);
            float ccx = fmaxf(xc, 0.0f), lowx = floorf(ccx);
            bool ex = lowx >= cap; lowx = fminf(lowx, cap);
            float highx = fminf(lowx + 1.0f, cap);
            float wfx = ex ? 0.0f : (ccx - lowx);
            int xl = (int)lowx, xh = (int)highx;
            if (vy && vx) {
                float v00 = plane[yl * HW + xl], v01 = plane[yl * HW + xh];
                float v10 = plane[yh * HW + xl], v11 = plane[yh * HW + xh];
                acc += (1.0f - wfy) * ((1.0f - wfx) * v00 + wfx * v01)
                     + wfy * ((1.0f - wfx) * v10 + wfx * v11);
            }
        }
    }
    out[idx] = acc * 0.25f;
}

extern "C" void kernel_launch(void* const* d_in, const int* in_sizes, int n_in,
                              void* d_out, int out_size, void* d_ws, size_t ws_size,
                              hipStream_t stream) {
    const float* f0    = (const float*)d_in[0];
    const float* f1    = (const float*)d_in[1];
    const float* f2    = (const float*)d_in[2];
    const float* f3    = (const float*)d_in[3];
    const float* boxes = (const float*)d_in[4];
    float* out = (float*)d_out;

    if (ws_size < WS_NEEDED) {
        const int total = B_ * R_ * C_ * OUTSZ * OUTSZ;
        roi_direct<<<(total + 255) / 256, 256, 0, stream>>>(f0, f1, f2, f3, boxes, out);
        return;
    }

    u16* nhwc = (u16*)d_ws;

    nhwc_cast<<<dim3(210, 4, 2), 512, 0, stream>>>(f0, f1, f2, f3, nhwc);
    roi_gather<<<dim3(2, N_), 512, 0, stream>>>(nhwc, boxes, out);
}